// Round 5
// baseline (159.878 us; speedup 1.0000x reference)
//
#include <hip/hip_runtime.h>
#include <math.h>

// Problem constants (fixed by the reference file)
#define OUT_H 7
#define OUT_W 7
#define GS 2                      // SAMPLE_NUM
#define NBINS (OUT_H * OUT_W)     // 49
#define NSAMP (GS * GS)           // 4
#define NMETA (NBINS * NSAMP)     // 196
#define SPATIAL_SCALE 0.25f
#define B_ 2
#define C_ 256
#define H_ 200
#define W_ 200
#define R_ 1000
#define HW_ (H_ * W_)             // 40000

typedef _Float16 half_t;
typedef __attribute__((ext_vector_type(8))) _Float16 half8;
typedef __attribute__((ext_vector_type(2))) _Float16 half2_t;
typedef __attribute__((ext_vector_type(4))) float f32x4;

// ============================================================================
// Fast path: XCD-banded roi order + fp16 NHWC transform + coalesced gather
// ============================================================================

// ---- NCHW fp32 -> NHWC fp16 tiled transpose (vectorized), with the
// roi->block permutation built by block (0,0,0).
// Swizzled LDS tile: float group g of row c stored at g ^ ((c^(c>>3))&7) ->
// conflict-free for both the b128 writes and the 8-consecutive-channel reads.
// tile: 64 channels x 64 hw. grid (625, 4, 2), block 256.
__global__ __launch_bounds__(256)
void nchw_to_nhwc_h(const float* __restrict__ in, half_t* __restrict__ out,
                    const float* __restrict__ rois, int* __restrict__ perm) {
    __shared__ float tile[64][64];       // 16 KB

    // ---- perm build (block 0 only; runs under the other blocks' traffic) ----
    __shared__ int cnt[8];
    __shared__ int novf, take;
    __shared__ unsigned char claimed[R_];
    __shared__ short ovf[R_];
    if (blockIdx.x == 0 && blockIdx.y == 0 && blockIdx.z == 0) {
        const int t0 = threadIdx.x;
        if (t0 < 8) cnt[t0] = 0;
        if (t0 == 0) { novf = 0; take = 0; }
        for (int t = t0; t < R_; t += 256) claimed[t] = 0;
        __syncthreads();
        for (int t = t0; t < R_; t += 256) {
            const float* roi = rois + t * 6;
            int   b   = (int)roi[0];
            float cyf = roi[2] * SPATIAL_SCALE;          // ~25..175
            int q = (int)((cyf - 25.0f) * (4.0f / 150.0f));
            q = q < 0 ? 0 : (q > 3 ? 3 : q);
            int band = b * 4 + q;
            band = band < 0 ? 0 : (band > 7 ? 7 : band);
            int rank = atomicAdd(&cnt[band], 1);
            if (rank < R_ / 8) {
                int id = band + 8 * rank;
                perm[id] = t;
                claimed[id] = 1;
            } else {
                ovf[atomicAdd(&novf, 1)] = (short)t;
            }
        }
        __syncthreads();
        for (int t = t0; t < R_; t += 256) {
            if (!claimed[t]) perm[t] = (int)ovf[atomicAdd(&take, 1)];
        }
    }

    const int hw0 = blockIdx.x * 64;     // 625 tiles
    const int c0  = blockIdx.y * 64;     // 4 chunks
    const int b   = blockIdx.z;
    const int t   = threadIdx.x;

    // read: f32x4 nontemporal (feat is read exactly once), 16 lanes per c-row
    {
        const f32x4* ip4 = (const f32x4*)(in + ((size_t)b * C_ + c0) * HW_ + hw0);
        const int r = t >> 4;            // 0..15
        const int q = t & 15;            // float4 index along hw
#pragma unroll
        for (int k = 0; k < 4; ++k) {
            const int c = r + 16 * k;
            f32x4 v = __builtin_nontemporal_load(&ip4[(size_t)c * (HW_ / 4) + q]);
            const int g = q ^ ((c ^ (c >> 3)) & 7);
            ((f32x4*)tile)[c * 16 + g] = v;
        }
    }
    __syncthreads();
    // write: thread = (hw row, 8-channel group); half8 16B stores
    {
        const int cg = t & 7;            // channel group (8 ch)
        const int hb = t >> 3;           // 0..31
        half_t* op = out + ((size_t)b * HW_ + hw0) * C_ + c0 + 8 * cg;
#pragma unroll
        for (int i = 0; i < 2; ++i) {
            const int hw = hb + 32 * i;
            const int gh = hw >> 2, oh = hw & 3;
            half8 h;
#pragma unroll
            for (int dc = 0; dc < 8; ++dc) {
                const int c = 8 * cg + dc;
                const float f = tile[c][4 * (gh ^ ((c ^ (c >> 3)) & 7)) + oh];
                h[dc] = (half_t)f;
            }
            *(half8*)(op + (size_t)hw * C_) = h;
        }
    }
}

// ---- mixed-precision FMA: acc += f16(half of pair) * w, fp32 accumulate ----
__device__ __forceinline__ void mix2(float& a0, float& a1,
                                     unsigned int pair, float w) {
    asm("v_fma_mix_f32 %0, %1, %2, %0 op_sel:[0,0,0] op_sel_hi:[1,0,0]"
        : "+v"(a0) : "v"(pair), "v"(w));
    asm("v_fma_mix_f32 %0, %1, %2, %0 op_sel:[1,0,0] op_sel_hi:[1,0,0]"
        : "+v"(a1) : "v"(pair), "v"(w));
}

// ---- register block of one bin's 16 taps (8B/lane each) ----
struct Taps { uint2 t[16]; };

__device__ __forceinline__ void load_taps(Taps& T, const uint2* __restrict__ fpu,
                                          const int4* __restrict__ s_o,
                                          int m, int lane) {
#pragma unroll
    for (int i = 0; i < 4; ++i) {
        const int4 o = s_o[m + i];
        T.t[4 * i + 0] = fpu[o.x + lane];
        T.t[4 * i + 1] = fpu[o.y + lane];
        T.t[4 * i + 2] = fpu[o.z + lane];
        T.t[4 * i + 3] = fpu[o.w + lane];
    }
}

__device__ __forceinline__ void fma_store(const Taps& T,
                                          const float4* __restrict__ s_w,
                                          int m, int j, int lane,
                                          float (&obuf)[4][64][NBINS]) {
    float ax = 0.0f, ay = 0.0f, az = 0.0f, aw = 0.0f;
#pragma unroll
    for (int i = 0; i < 4; ++i) {
        const float4 w = s_w[m + i];
        mix2(ax, ay, T.t[4 * i + 0].x, w.x); mix2(az, aw, T.t[4 * i + 0].y, w.x);
        mix2(ax, ay, T.t[4 * i + 1].x, w.y); mix2(az, aw, T.t[4 * i + 1].y, w.y);
        mix2(ax, ay, T.t[4 * i + 2].x, w.z); mix2(az, aw, T.t[4 * i + 2].y, w.z);
        mix2(ax, ay, T.t[4 * i + 3].x, w.w); mix2(az, aw, T.t[4 * i + 3].y, w.w);
    }
    // dword index stride per lane = 49 (odd) -> 32 distinct banks, free
    obuf[0][lane][j] = ax;   // c = 4*lane+0
    obuf[1][lane][j] = ay;   // c = 4*lane+1
    obuf[2][lane][j] = az;   // c = 4*lane+2
    obuf[3][lane][j] = aw;   // c = 4*lane+3
}

// ---- gather from fp16 NHWC: one block (1024 thr, 16 waves) per roi.
// TLP instead of per-wave pipelining: rounds 3-4 showed 2-deep ping-pong at
// 16 waves/CU gains ~nothing (latency >> FMA block; compiler fights the
// register pressure). Here: single-buffered taps (small body, <=64 VGPR via
// launch_bounds(1024,8)) and 2 blocks/CU x 16 waves = 32 waves/CU (100%
// occupancy) -> 512 tap loads in flight per CU from thread parallelism.
// Full-roi obuf (all 49 bins) -> ONE coalesced line-complete nontemporal
// writeout (no partial-line RMW).
__global__ __launch_bounds__(1024, 8)
void gather_nhwc(const half_t* __restrict__ nhwc,
                 const float* __restrict__ rois,
                 const int* __restrict__ perm,
                 float* __restrict__ out) {
    __shared__ float  obuf[4][64][NBINS];   // 50176 B
    __shared__ int4   s_o[NMETA];           // 3136 B
    __shared__ float4 s_w[NMETA];           // 3136 B

    const int r    = perm[blockIdx.x];
    const int tid  = threadIdx.x;
    const int wave = tid >> 6;   // 0..15
    const int lane = tid & 63;

    // ---- phase 0: per-(bin,sample) metadata (196 of 1024 threads) ----
    if (tid < NMETA) {
        const float* roi = rois + r * 6;
        const int   b     = (int)roi[0];
        const float cx    = roi[1] * SPATIAL_SCALE - 0.5f;   // ALIGNED
        const float cy    = roi[2] * SPATIAL_SCALE - 0.5f;
        const float rw    = roi[3] * SPATIAL_SCALE;
        const float rh    = roi[4] * SPATIAL_SCALE;
        const float theta = roi[5];                           // CLOCKWISE == False
        const float bin_h = rh * (1.0f / OUT_H);
        const float bin_w = rw * (1.0f / OUT_W);
        float st, ct;
        __sincosf(theta, &st, &ct);

        const int bin = tid >> 2;          // 0..48
        const int s   = tid & 3;           // 0..3
        const int ph  = bin / OUT_W, pw = bin % OUT_W;
        const int iy  = s >> 1,      ix = s & 1;

        const float yy = -rh * 0.5f + ((float)ph + ((float)iy + 0.5f) * 0.5f) * bin_h;
        const float xx = -rw * 0.5f + ((float)pw + ((float)ix + 0.5f) * 0.5f) * bin_w;
        float x = yy * st + xx * ct + cx;
        float y = yy * ct - xx * st + cy;

        const bool valid = (y > -1.0f) && (y < (float)H_) &&
                           (x > -1.0f) && (x < (float)W_);
        y = fmaxf(y, 0.0f);
        x = fmaxf(x, 0.0f);
        int yl = (int)y, xl = (int)x;
        int yh; float ly;
        if (yl >= H_ - 1) { yl = H_ - 1; yh = H_ - 1; ly = 0.0f; }
        else              { yh = yl + 1; ly = y - (float)yl; }
        int xh; float lx;
        if (xl >= W_ - 1) { xl = W_ - 1; xh = W_ - 1; lx = 0.0f; }
        else              { xh = xl + 1; lx = x - (float)xl; }
        const float hy = 1.0f - ly, hx = 1.0f - lx;
        const float scale = valid ? (1.0f / NSAMP) : 0.0f;

        const int bplane = b * HW_;
        s_o[tid] = make_int4((bplane + yl * W_ + xl) * (C_ / 4),
                             (bplane + yl * W_ + xh) * (C_ / 4),
                             (bplane + yh * W_ + xl) * (C_ / 4),
                             (bplane + yh * W_ + xh) * (C_ / 4));
        s_w[tid] = make_float4(hy * hx * scale, hy * lx * scale,
                               ly * hx * scale, ly * lx * scale);
    }
    __syncthreads();

    const uint2* __restrict__ fpu = (const uint2*)nhwc;

    // ---- bin loop: wave w owns bins w, w+16, w+32, w+48 (<49) ----
    for (int j = wave; j < NBINS; j += 16) {
        Taps T;
        load_taps(T, fpu, s_o, 4 * j, lane);
        fma_store(T, s_w, 4 * j, j, lane, obuf);
    }
    __syncthreads();

    // ---- single coalesced writeout: 12544 consecutive floats per roi ----
    // (write-once data: nontemporal, keep L2 for the tap band)
    float* out_r = out + (size_t)r * (C_ * NBINS);
    const int E = C_ * NBINS;            // 12544
#pragma unroll
    for (int i = 0; i < (E + 1023) / 1024; ++i) {
        const int f = tid + 1024 * i;
        if (f < E) {
            const int c = f / NBINS;
            const int j = f - c * NBINS;
            __builtin_nontemporal_store(obuf[c & 3][c >> 2][j], &out_r[f]);
        }
    }
}

// ============================================================================
// Fallback path (round-0 structure, known-passing)
// ============================================================================

struct alignas(16) Samp {
    int o0, o1, o2, o3;
    float w0, w1, w2, w3;
};

__device__ __forceinline__ Samp compute_samp(const float* __restrict__ rois,
                                             int r, int ph, int pw, int s) {
    const float* roi = rois + r * 6;
    int   b     = (int)roi[0];
    float cx    = roi[1] * SPATIAL_SCALE - 0.5f;
    float cy    = roi[2] * SPATIAL_SCALE - 0.5f;
    float rw    = roi[3] * SPATIAL_SCALE;
    float rh    = roi[4] * SPATIAL_SCALE;
    float theta = roi[5];
    float bin_h = rh * (1.0f / OUT_H);
    float bin_w = rw * (1.0f / OUT_W);
    int iy = s / GS, ix = s % GS;
    float yy = -rh * 0.5f + ((float)ph + ((float)iy + 0.5f) * (1.0f / GS)) * bin_h;
    float xx = -rw * 0.5f + ((float)pw + ((float)ix + 0.5f) * (1.0f / GS)) * bin_w;
    float st = sinf(theta), ct = cosf(theta);
    float x = yy * st + xx * ct + cx;
    float y = yy * ct - xx * st + cy;
    bool valid = (y > -1.0f) && (y < (float)H_) && (x > -1.0f) && (x < (float)W_);
    y = fmaxf(y, 0.0f);
    x = fmaxf(x, 0.0f);
    int yl = (int)y;
    int xl = (int)x;
    int yh; float ly;
    if (yl >= H_ - 1) { yl = H_ - 1; yh = H_ - 1; ly = 0.0f; }
    else              { yh = yl + 1; ly = y - (float)yl; }
    int xh; float lx;
    if (xl >= W_ - 1) { xl = W_ - 1; xh = W_ - 1; lx = 0.0f; }
    else              { xh = xl + 1; lx = x - (float)xl; }
    float hy = 1.0f - ly, hx = 1.0f - lx;
    float scale = valid ? (1.0f / NSAMP) : 0.0f;
    Samp sp;
    int base = b * (C_ * H_ * W_);
    sp.o0 = base + yl * W_ + xl;
    sp.o1 = base + yl * W_ + xh;
    sp.o2 = base + yh * W_ + xl;
    sp.o3 = base + yh * W_ + xh;
    sp.w0 = hy * hx * scale;
    sp.w1 = hy * lx * scale;
    sp.w2 = ly * hx * scale;
    sp.w3 = ly * lx * scale;
    return sp;
}

__global__ __launch_bounds__(256)
void mono_kernel(const float* __restrict__ feat,
                 const float* __restrict__ rois,
                 float* __restrict__ out) {
    int tid = blockIdx.x * blockDim.x + threadIdx.x;
    if (tid >= R_ * C_ * NBINS) return;
    int bin = tid % NBINS;
    int rc  = tid / NBINS;
    int c   = rc % C_;
    int r   = rc / C_;
    int coff = c * (H_ * W_);
    float acc = 0.0f;
#pragma unroll
    for (int s = 0; s < NSAMP; ++s) {
        Samp t = compute_samp(rois, r, bin / OUT_W, bin % OUT_W, s);
        acc += t.w0 * feat[coff + t.o0];
        acc += t.w1 * feat[coff + t.o1];
        acc += t.w2 * feat[coff + t.o2];
        acc += t.w3 * feat[coff + t.o3];
    }
    out[tid] = acc;
}

// ============================================================================

extern "C" void kernel_launch(void* const* d_in, const int* in_sizes, int n_in,
                              void* d_out, int out_size, void* d_ws, size_t ws_size,
                              hipStream_t stream) {
    const float* feat = (const float*)d_in[0];
    const float* rois = (const float*)d_in[1];
    float* out = (float*)d_out;

    const size_t nhwc_bytes = (size_t)B_ * C_ * HW_ * sizeof(half_t);  // 41 MB
    const size_t perm_bytes = (size_t)R_ * sizeof(int);

    if (ws_size >= nhwc_bytes + perm_bytes) {
        half_t* nhwc = (half_t*)d_ws;
        int*    perm = (int*)((char*)d_ws + nhwc_bytes);
        dim3 tgrid(HW_ / 64, C_ / 64, B_);   // 625 x 4 x 2
        nchw_to_nhwc_h<<<tgrid, 256, 0, stream>>>(feat, nhwc, rois, perm);
        gather_nhwc<<<R_, 1024, 0, stream>>>(nhwc, rois, perm, out);
    } else {
        const int n_out = R_ * C_ * NBINS;
        mono_kernel<<<(n_out + 255) / 256, 256, 0, stream>>>(feat, rois, out);
    }
}

// Round 6
// 157.920 us; speedup vs baseline: 1.0124x; 1.0124x over previous
//
#include <hip/hip_runtime.h>
#include <math.h>

// Problem constants (fixed by the reference file)
#define OUT_H 7
#define OUT_W 7
#define GS 2                      // SAMPLE_NUM
#define NBINS (OUT_H * OUT_W)     // 49
#define NSAMP (GS * GS)           // 4
#define NMETA (NBINS * NSAMP)     // 196
#define SPATIAL_SCALE 0.25f
#define B_ 2
#define C_ 256
#define H_ 200
#define W_ 200
#define R_ 1000
#define HW_ (H_ * W_)             // 40000

typedef _Float16 half_t;
typedef __attribute__((ext_vector_type(8))) _Float16 half8;
typedef __attribute__((ext_vector_type(2))) _Float16 half2_t;
typedef __attribute__((ext_vector_type(4))) float f32x4;

// ============================================================================
// Fast path: XCD-banded + cx-sorted roi order + fp16 NHWC + coalesced gather
// ============================================================================

// ---- NCHW fp32 -> NHWC fp16 tiled transpose (vectorized), with the
// roi->block permutation built by block (0,0,0).
//
// Perm design: slot%8 = band = (batch, cy-quartile) -> one XCD's L2 holds one
// spatial cy-slab. NEW this round: within each band, slots are ordered by a
// 64-bucket cx counting sort. The ~64 blocks of a band that are co-resident
// on an XCD at any instant then share a compact cy-slab x partial-cx patch
// (~5MB, L2-fittable) instead of sampling the whole ~9MB band randomly ->
// tap misses move from L3 (~650cyc) to L2 (~200cyc), which is the service
// rate limiter (rounds 3-5: ILP/TLP changes were all neutral).
__global__ __launch_bounds__(256)
void nchw_to_nhwc_h(const float* __restrict__ in, half_t* __restrict__ out,
                    const float* __restrict__ rois, int* __restrict__ perm) {
    __shared__ float tile[64][64];       // 16 KB

    // ---- perm build (block 0 only; runs under the other blocks' traffic) ----
    __shared__ int bpos[8][64];          // per-(band,cx-bucket) running offset
    __shared__ int novf, take;
    __shared__ unsigned char claimed[R_];
    __shared__ short ovf[R_];
    if (blockIdx.x == 0 && blockIdx.y == 0 && blockIdx.z == 0) {
        const int t0 = threadIdx.x;
        // zero histogram
        for (int i = t0; i < 8 * 64; i += 256) ((int*)bpos)[i] = 0;
        if (t0 == 0) { novf = 0; take = 0; }
        for (int t = t0; t < R_; t += 256) claimed[t] = 0;
        __syncthreads();
        // pass 1: histogram of (band, cx-bucket)
        for (int t = t0; t < R_; t += 256) {
            const float* roi = rois + t * 6;
            int   b   = (int)roi[0];
            float cyf = roi[2] * SPATIAL_SCALE;          // ~25..175
            float cxf = roi[1] * SPATIAL_SCALE;          // ~25..175
            int q = (int)((cyf - 25.0f) * (4.0f / 150.0f));
            q = q < 0 ? 0 : (q > 3 ? 3 : q);
            int band = b * 4 + q;
            band = band < 0 ? 0 : (band > 7 ? 7 : band);
            int bk = (int)((cxf - 25.0f) * (64.0f / 150.0f));
            bk = bk < 0 ? 0 : (bk > 63 ? 63 : bk);
            atomicAdd(&bpos[band][bk], 1);
        }
        __syncthreads();
        // exclusive prefix per band (8 threads, serial 64 each)
        if (t0 < 8) {
            int s = 0;
            for (int k = 0; k < 64; ++k) {
                int c = bpos[t0][k];
                bpos[t0][k] = s;
                s += c;
            }
        }
        __syncthreads();
        // pass 2: place sorted-by-cx within band; band overflow -> spill list
        for (int t = t0; t < R_; t += 256) {
            const float* roi = rois + t * 6;
            int   b   = (int)roi[0];
            float cyf = roi[2] * SPATIAL_SCALE;
            float cxf = roi[1] * SPATIAL_SCALE;
            int q = (int)((cyf - 25.0f) * (4.0f / 150.0f));
            q = q < 0 ? 0 : (q > 3 ? 3 : q);
            int band = b * 4 + q;
            band = band < 0 ? 0 : (band > 7 ? 7 : band);
            int bk = (int)((cxf - 25.0f) * (64.0f / 150.0f));
            bk = bk < 0 ? 0 : (bk > 63 ? 63 : bk);
            int pos = atomicAdd(&bpos[band][bk], 1);
            if (pos < R_ / 8) {
                int id = band + 8 * pos;
                perm[id] = t;
                claimed[id] = 1;
            } else {
                ovf[atomicAdd(&novf, 1)] = (short)t;
            }
        }
        __syncthreads();
        for (int t = t0; t < R_; t += 256) {
            if (!claimed[t]) perm[t] = (int)ovf[atomicAdd(&take, 1)];
        }
    }

    const int hw0 = blockIdx.x * 64;     // 625 tiles
    const int c0  = blockIdx.y * 64;     // 4 chunks
    const int b   = blockIdx.z;
    const int t   = threadIdx.x;

    // read: f32x4 nontemporal (feat is read exactly once), 16 lanes per c-row
    {
        const f32x4* ip4 = (const f32x4*)(in + ((size_t)b * C_ + c0) * HW_ + hw0);
        const int r = t >> 4;            // 0..15
        const int q = t & 15;            // float4 index along hw
#pragma unroll
        for (int k = 0; k < 4; ++k) {
            const int c = r + 16 * k;
            f32x4 v = __builtin_nontemporal_load(&ip4[(size_t)c * (HW_ / 4) + q]);
            const int g = q ^ ((c ^ (c >> 3)) & 7);
            ((f32x4*)tile)[c * 16 + g] = v;
        }
    }
    __syncthreads();
    // write: thread = (hw row, 8-channel group); half8 16B stores
    {
        const int cg = t & 7;            // channel group (8 ch)
        const int hb = t >> 3;           // 0..31
        half_t* op = out + ((size_t)b * HW_ + hw0) * C_ + c0 + 8 * cg;
#pragma unroll
        for (int i = 0; i < 2; ++i) {
            const int hw = hb + 32 * i;
            const int gh = hw >> 2, oh = hw & 3;
            half8 h;
#pragma unroll
            for (int dc = 0; dc < 8; ++dc) {
                const int c = 8 * cg + dc;
                const float f = tile[c][4 * (gh ^ ((c ^ (c >> 3)) & 7)) + oh];
                h[dc] = (half_t)f;
            }
            *(half8*)(op + (size_t)hw * C_) = h;
        }
    }
}

// ---- mixed-precision FMA: acc += f16(half of pair) * w, fp32 accumulate ----
__device__ __forceinline__ void mix2(float& a0, float& a1,
                                     unsigned int pair, float w) {
    asm("v_fma_mix_f32 %0, %1, %2, %0 op_sel:[0,0,0] op_sel_hi:[1,0,0]"
        : "+v"(a0) : "v"(pair), "v"(w));
    asm("v_fma_mix_f32 %0, %1, %2, %0 op_sel:[1,0,0] op_sel_hi:[1,0,0]"
        : "+v"(a1) : "v"(pair), "v"(w));
}

// ---- register block of one bin's 16 taps (8B/lane each) ----
struct Taps { uint2 t[16]; };

__device__ __forceinline__ void load_taps(Taps& T, const uint2* __restrict__ fpu,
                                          const int4* __restrict__ s_o,
                                          int m, int lane) {
#pragma unroll
    for (int i = 0; i < 4; ++i) {
        const int4 o = s_o[m + i];
        T.t[4 * i + 0] = fpu[o.x + lane];
        T.t[4 * i + 1] = fpu[o.y + lane];
        T.t[4 * i + 2] = fpu[o.z + lane];
        T.t[4 * i + 3] = fpu[o.w + lane];
    }
}

__device__ __forceinline__ void fma_store(const Taps& T,
                                          const float4* __restrict__ s_w,
                                          int m, int j, int lane,
                                          float (&obuf)[4][64][NBINS]) {
    float ax = 0.0f, ay = 0.0f, az = 0.0f, aw = 0.0f;
#pragma unroll
    for (int i = 0; i < 4; ++i) {
        const float4 w = s_w[m + i];
        mix2(ax, ay, T.t[4 * i + 0].x, w.x); mix2(az, aw, T.t[4 * i + 0].y, w.x);
        mix2(ax, ay, T.t[4 * i + 1].x, w.y); mix2(az, aw, T.t[4 * i + 1].y, w.y);
        mix2(ax, ay, T.t[4 * i + 2].x, w.z); mix2(az, aw, T.t[4 * i + 2].y, w.z);
        mix2(ax, ay, T.t[4 * i + 3].x, w.w); mix2(az, aw, T.t[4 * i + 3].y, w.w);
    }
    // dword index stride per lane = 49 (odd) -> 32 distinct banks, free
    obuf[0][lane][j] = ax;   // c = 4*lane+0
    obuf[1][lane][j] = ay;   // c = 4*lane+1
    obuf[2][lane][j] = az;   // c = 4*lane+2
    obuf[3][lane][j] = aw;   // c = 4*lane+3
}

// ---- gather from fp16 NHWC: one block (512 thr, 8 waves) per roi.
// Round-4 structure (best measured): full-roi obuf, one coalesced
// line-complete nontemporal writeout, sched_barrier-pinned 2-deep ping-pong.
// LDS 56.4KB -> 2 blocks/CU; launch_bounds(512,4) -> 128-VGPR budget.
__global__ __launch_bounds__(512, 4)
void gather_nhwc(const half_t* __restrict__ nhwc,
                 const float* __restrict__ rois,
                 const int* __restrict__ perm,
                 float* __restrict__ out) {
    __shared__ float  obuf[4][64][NBINS];   // 50176 B
    __shared__ int4   s_o[NMETA];           // 3136 B
    __shared__ float4 s_w[NMETA];           // 3136 B

    const int r    = perm[blockIdx.x];
    const int tid  = threadIdx.x;
    const int wave = tid >> 6;   // 0..7
    const int lane = tid & 63;

    // ---- phase 0: per-(bin,sample) metadata (196 of 512 threads) ----
    if (tid < NMETA) {
        const float* roi = rois + r * 6;
        const int   b     = (int)roi[0];
        const float cx    = roi[1] * SPATIAL_SCALE - 0.5f;   // ALIGNED
        const float cy    = roi[2] * SPATIAL_SCALE - 0.5f;
        const float rw    = roi[3] * SPATIAL_SCALE;
        const float rh    = roi[4] * SPATIAL_SCALE;
        const float theta = roi[5];                           // CLOCKWISE == False
        const float bin_h = rh * (1.0f / OUT_H);
        const float bin_w = rw * (1.0f / OUT_W);
        float st, ct;
        __sincosf(theta, &st, &ct);

        const int bin = tid >> 2;          // 0..48
        const int s   = tid & 3;           // 0..3
        const int ph  = bin / OUT_W, pw = bin % OUT_W;
        const int iy  = s >> 1,      ix = s & 1;

        const float yy = -rh * 0.5f + ((float)ph + ((float)iy + 0.5f) * 0.5f) * bin_h;
        const float xx = -rw * 0.5f + ((float)pw + ((float)ix + 0.5f) * 0.5f) * bin_w;
        float x = yy * st + xx * ct + cx;
        float y = yy * ct - xx * st + cy;

        const bool valid = (y > -1.0f) && (y < (float)H_) &&
                           (x > -1.0f) && (x < (float)W_);
        y = fmaxf(y, 0.0f);
        x = fmaxf(x, 0.0f);
        int yl = (int)y, xl = (int)x;
        int yh; float ly;
        if (yl >= H_ - 1) { yl = H_ - 1; yh = H_ - 1; ly = 0.0f; }
        else              { yh = yl + 1; ly = y - (float)yl; }
        int xh; float lx;
        if (xl >= W_ - 1) { xl = W_ - 1; xh = W_ - 1; lx = 0.0f; }
        else              { xh = xl + 1; lx = x - (float)xl; }
        const float hy = 1.0f - ly, hx = 1.0f - lx;
        const float scale = valid ? (1.0f / NSAMP) : 0.0f;

        const int bplane = b * HW_;
        s_o[tid] = make_int4((bplane + yl * W_ + xl) * (C_ / 4),
                             (bplane + yl * W_ + xh) * (C_ / 4),
                             (bplane + yh * W_ + xl) * (C_ / 4),
                             (bplane + yh * W_ + xh) * (C_ / 4));
        s_w[tid] = make_float4(hy * hx * scale, hy * lx * scale,
                               ly * hx * scale, ly * lx * scale);
    }
    __syncthreads();

    const uint2* __restrict__ fpu = (const uint2*)nhwc;

    // ---- ping-pong pipelined bin loop, schedule pinned by sched_barrier ----
    // Wave w owns bins w, w+8, ..., <49 (6 or 7 bins). Buffer A serves
    // w, w+16, w+32, w+48; buffer B serves w+8, w+24, w+40. All branch
    // conditions are wave-uniform.
    {
        Taps A, B;
        int jA = wave;
        int jB = wave + 8;
        load_taps(A, fpu, s_o, 4 * jA, lane);
        if (jB < NBINS) load_taps(B, fpu, s_o, 4 * jB, lane);
        __builtin_amdgcn_sched_barrier(0);

        // stage 1
        fma_store(A, s_w, 4 * jA, jA, lane, obuf);
        jA += 16;
        if (jA < NBINS) load_taps(A, fpu, s_o, 4 * jA, lane);
        __builtin_amdgcn_sched_barrier(0);
        if (jB < NBINS) {
            fma_store(B, s_w, 4 * jB, jB, lane, obuf);
            jB += 16;
            if (jB < NBINS) load_taps(B, fpu, s_o, 4 * jB, lane);
            __builtin_amdgcn_sched_barrier(0);
        }
        // stage 2
        if (jA < NBINS) {
            fma_store(A, s_w, 4 * jA, jA, lane, obuf);
            jA += 16;
            if (jA < NBINS) load_taps(A, fpu, s_o, 4 * jA, lane);
            __builtin_amdgcn_sched_barrier(0);
        }
        if (jB < NBINS) {
            fma_store(B, s_w, 4 * jB, jB, lane, obuf);
            jB += 16;
            if (jB < NBINS) load_taps(B, fpu, s_o, 4 * jB, lane);
            __builtin_amdgcn_sched_barrier(0);
        }
        // stage 3
        if (jA < NBINS) {
            fma_store(A, s_w, 4 * jA, jA, lane, obuf);
            jA += 16;
            if (jA < NBINS) load_taps(A, fpu, s_o, 4 * jA, lane);
            __builtin_amdgcn_sched_barrier(0);
        }
        if (jB < NBINS) {
            fma_store(B, s_w, 4 * jB, jB, lane, obuf);
            jB += 16;            // max start 15 -> last use at 47; no reload
        }
        // stage 4 (wave 0 only: jA == 48)
        if (jA < NBINS) {
            fma_store(A, s_w, 4 * jA, jA, lane, obuf);
        }
    }
    __syncthreads();

    // ---- single coalesced writeout: 12544 consecutive floats per roi ----
    // (write-once data: nontemporal, keep L2 for the tap band)
    float* out_r = out + (size_t)r * (C_ * NBINS);
    const int E = C_ * NBINS;            // 12544
#pragma unroll
    for (int i = 0; i < (E + 511) / 512; ++i) {
        const int f = tid + 512 * i;
        if (f < E) {
            const int c = f / NBINS;
            const int j = f - c * NBINS;
            __builtin_nontemporal_store(obuf[c & 3][c >> 2][j], &out_r[f]);
        }
    }
}

// ============================================================================
// Fallback path (round-0 structure, known-passing)
// ============================================================================

struct alignas(16) Samp {
    int o0, o1, o2, o3;
    float w0, w1, w2, w3;
};

__device__ __forceinline__ Samp compute_samp(const float* __restrict__ rois,
                                             int r, int ph, int pw, int s) {
    const float* roi = rois + r * 6;
    int   b     = (int)roi[0];
    float cx    = roi[1] * SPATIAL_SCALE - 0.5f;
    float cy    = roi[2] * SPATIAL_SCALE - 0.5f;
    float rw    = roi[3] * SPATIAL_SCALE;
    float rh    = roi[4] * SPATIAL_SCALE;
    float theta = roi[5];
    float bin_h = rh * (1.0f / OUT_H);
    float bin_w = rw * (1.0f / OUT_W);
    int iy = s / GS, ix = s % GS;
    float yy = -rh * 0.5f + ((float)ph + ((float)iy + 0.5f) * (1.0f / GS)) * bin_h;
    float xx = -rw * 0.5f + ((float)pw + ((float)ix + 0.5f) * (1.0f / GS)) * bin_w;
    float st = sinf(theta), ct = cosf(theta);
    float x = yy * st + xx * ct + cx;
    float y = yy * ct - xx * st + cy;
    bool valid = (y > -1.0f) && (y < (float)H_) && (x > -1.0f) && (x < (float)W_);
    y = fmaxf(y, 0.0f);
    x = fmaxf(x, 0.0f);
    int yl = (int)y;
    int xl = (int)x;
    int yh; float ly;
    if (yl >= H_ - 1) { yl = H_ - 1; yh = H_ - 1; ly = 0.0f; }
    else              { yh = yl + 1; ly = y - (float)yl; }
    int xh; float lx;
    if (xl >= W_ - 1) { xl = W_ - 1; xh = W_ - 1; lx = 0.0f; }
    else              { xh = xl + 1; lx = x - (float)xl; }
    float hy = 1.0f - ly, hx = 1.0f - lx;
    float scale = valid ? (1.0f / NSAMP) : 0.0f;
    Samp sp;
    int base = b * (C_ * H_ * W_);
    sp.o0 = base + yl * W_ + xl;
    sp.o1 = base + yl * W_ + xh;
    sp.o2 = base + yh * W_ + xl;
    sp.o3 = base + yh * W_ + xh;
    sp.w0 = hy * hx * scale;
    sp.w1 = hy * lx * scale;
    sp.w2 = ly * hx * scale;
    sp.w3 = ly * lx * scale;
    return sp;
}

__global__ __launch_bounds__(256)
void mono_kernel(const float* __restrict__ feat,
                 const float* __restrict__ rois,
                 float* __restrict__ out) {
    int tid = blockIdx.x * blockDim.x + threadIdx.x;
    if (tid >= R_ * C_ * NBINS) return;
    int bin = tid % NBINS;
    int rc  = tid / NBINS;
    int c   = rc % C_;
    int r   = rc / C_;
    int coff = c * (H_ * W_);
    float acc = 0.0f;
#pragma unroll
    for (int s = 0; s < NSAMP; ++s) {
        Samp t = compute_samp(rois, r, bin / OUT_W, bin % OUT_W, s);
        acc += t.w0 * feat[coff + t.o0];
        acc += t.w1 * feat[coff + t.o1];
        acc += t.w2 * feat[coff + t.o2];
        acc += t.w3 * feat[coff + t.o3];
    }
    out[tid] = acc;
}

// ============================================================================

extern "C" void kernel_launch(void* const* d_in, const int* in_sizes, int n_in,
                              void* d_out, int out_size, void* d_ws, size_t ws_size,
                              hipStream_t stream) {
    const float* feat = (const float*)d_in[0];
    const float* rois = (const float*)d_in[1];
    float* out = (float*)d_out;

    const size_t nhwc_bytes = (size_t)B_ * C_ * HW_ * sizeof(half_t);  // 41 MB
    const size_t perm_bytes = (size_t)R_ * sizeof(int);

    if (ws_size >= nhwc_bytes + perm_bytes) {
        half_t* nhwc = (half_t*)d_ws;
        int*    perm = (int*)((char*)d_ws + nhwc_bytes);
        dim3 tgrid(HW_ / 64, C_ / 64, B_);   // 625 x 4 x 2
        nchw_to_nhwc_h<<<tgrid, 256, 0, stream>>>(feat, nhwc, rois, perm);
        gather_nhwc<<<R_, 512, 0, stream>>>(nhwc, rois, perm, out);
    } else {
        const int n_out = R_ * C_ * NBINS;
        mono_kernel<<<(n_out + 255) / 256, 256, 0, stream>>>(feat, rois, out);
    }
}

// Round 7
// 151.496 us; speedup vs baseline: 1.0553x; 1.0424x over previous
//
#include <hip/hip_runtime.h>
#include <math.h>

// Problem constants (fixed by the reference file)
#define OUT_H 7
#define OUT_W 7
#define GS 2                      // SAMPLE_NUM
#define NBINS (OUT_H * OUT_W)     // 49
#define NSAMP (GS * GS)           // 4
#define NMETA (NBINS * NSAMP)     // 196
#define SPATIAL_SCALE 0.25f
#define B_ 2
#define C_ 256
#define H_ 200
#define W_ 200
#define R_ 1000
#define HW_ (H_ * W_)             // 40000

typedef _Float16 half_t;
typedef __attribute__((ext_vector_type(8))) _Float16 half8;
typedef __attribute__((ext_vector_type(2))) _Float16 half2_t;
typedef __attribute__((ext_vector_type(4))) float f32x4;

// ============================================================================
// Fast path: XCD-banded + cx-sorted roi order + fp16 NHWC + paired-load gather
// ============================================================================

// ---- NCHW fp32 -> NHWC fp16 tiled transpose (vectorized), with the
// roi->block permutation built by block (0,0,0).
// Perm: slot%8 = (batch, cy-quartile) band -> XCD L2 holds one spatial slab;
// within band, cx counting sort keeps co-resident blocks in a compact patch.
__global__ __launch_bounds__(256)
void nchw_to_nhwc_h(const float* __restrict__ in, half_t* __restrict__ out,
                    const float* __restrict__ rois, int* __restrict__ perm) {
    __shared__ float tile[64][64];       // 16 KB

    // ---- perm build (block 0 only; runs under the other blocks' traffic) ----
    __shared__ int bpos[8][64];          // per-(band,cx-bucket) running offset
    __shared__ int novf, take;
    __shared__ unsigned char claimed[R_];
    __shared__ short ovf[R_];
    if (blockIdx.x == 0 && blockIdx.y == 0 && blockIdx.z == 0) {
        const int t0 = threadIdx.x;
        for (int i = t0; i < 8 * 64; i += 256) ((int*)bpos)[i] = 0;
        if (t0 == 0) { novf = 0; take = 0; }
        for (int t = t0; t < R_; t += 256) claimed[t] = 0;
        __syncthreads();
        for (int t = t0; t < R_; t += 256) {
            const float* roi = rois + t * 6;
            int   b   = (int)roi[0];
            float cyf = roi[2] * SPATIAL_SCALE;
            float cxf = roi[1] * SPATIAL_SCALE;
            int q = (int)((cyf - 25.0f) * (4.0f / 150.0f));
            q = q < 0 ? 0 : (q > 3 ? 3 : q);
            int band = b * 4 + q;
            band = band < 0 ? 0 : (band > 7 ? 7 : band);
            int bk = (int)((cxf - 25.0f) * (64.0f / 150.0f));
            bk = bk < 0 ? 0 : (bk > 63 ? 63 : bk);
            atomicAdd(&bpos[band][bk], 1);
        }
        __syncthreads();
        if (t0 < 8) {
            int s = 0;
            for (int k = 0; k < 64; ++k) {
                int c = bpos[t0][k];
                bpos[t0][k] = s;
                s += c;
            }
        }
        __syncthreads();
        for (int t = t0; t < R_; t += 256) {
            const float* roi = rois + t * 6;
            int   b   = (int)roi[0];
            float cyf = roi[2] * SPATIAL_SCALE;
            float cxf = roi[1] * SPATIAL_SCALE;
            int q = (int)((cyf - 25.0f) * (4.0f / 150.0f));
            q = q < 0 ? 0 : (q > 3 ? 3 : q);
            int band = b * 4 + q;
            band = band < 0 ? 0 : (band > 7 ? 7 : band);
            int bk = (int)((cxf - 25.0f) * (64.0f / 150.0f));
            bk = bk < 0 ? 0 : (bk > 63 ? 63 : bk);
            int pos = atomicAdd(&bpos[band][bk], 1);
            if (pos < R_ / 8) {
                int id = band + 8 * pos;
                perm[id] = t;
                claimed[id] = 1;
            } else {
                ovf[atomicAdd(&novf, 1)] = (short)t;
            }
        }
        __syncthreads();
        for (int t = t0; t < R_; t += 256) {
            if (!claimed[t]) perm[t] = (int)ovf[atomicAdd(&take, 1)];
        }
    }

    const int hw0 = blockIdx.x * 64;     // 625 tiles
    const int c0  = blockIdx.y * 64;     // 4 chunks
    const int b   = blockIdx.z;
    const int t   = threadIdx.x;

    // read: f32x4 nontemporal (feat is read exactly once), 16 lanes per c-row
    {
        const f32x4* ip4 = (const f32x4*)(in + ((size_t)b * C_ + c0) * HW_ + hw0);
        const int r = t >> 4;            // 0..15
        const int q = t & 15;            // float4 index along hw
#pragma unroll
        for (int k = 0; k < 4; ++k) {
            const int c = r + 16 * k;
            f32x4 v = __builtin_nontemporal_load(&ip4[(size_t)c * (HW_ / 4) + q]);
            const int g = q ^ ((c ^ (c >> 3)) & 7);
            ((f32x4*)tile)[c * 16 + g] = v;
        }
    }
    __syncthreads();
    // write: thread = (hw row, 8-channel group); half8 16B stores
    {
        const int cg = t & 7;            // channel group (8 ch)
        const int hb = t >> 3;           // 0..31
        half_t* op = out + ((size_t)b * HW_ + hw0) * C_ + c0 + 8 * cg;
#pragma unroll
        for (int i = 0; i < 2; ++i) {
            const int hw = hb + 32 * i;
            const int gh = hw >> 2, oh = hw & 3;
            half8 h;
#pragma unroll
            for (int dc = 0; dc < 8; ++dc) {
                const int c = 8 * cg + dc;
                const float f = tile[c][4 * (gh ^ ((c ^ (c >> 3)) & 7)) + oh];
                h[dc] = (half_t)f;
            }
            *(half8*)(op + (size_t)hw * C_) = h;
        }
    }
}

// ---- mixed-precision FMA: acc += f16(half of pair) * w, fp32 accumulate ----
__device__ __forceinline__ void mix2(float& a0, float& a1,
                                     unsigned int pair, float w) {
    asm("v_fma_mix_f32 %0, %1, %2, %0 op_sel:[0,0,0] op_sel_hi:[1,0,0]"
        : "+v"(a0) : "v"(pair), "v"(w));
    asm("v_fma_mix_f32 %0, %1, %2, %0 op_sel:[1,0,0] op_sel_hi:[1,0,0]"
        : "+v"(a1) : "v"(pair), "v"(w));
}

// ---- 8-channel accumulate of one 16B pair fragment ----
__device__ __forceinline__ void mix8(float (&a)[8], const uint4& t, float w) {
    mix2(a[0], a[1], t.x, w); mix2(a[2], a[3], t.y, w);
    mix2(a[4], a[5], t.z, w); mix2(a[6], a[7], t.w, w);
}

// ---- register block of one bin's 8 PAIRED tap loads (16B/lane each) ----
// A pair = two x-adjacent pixels (1024B contiguous): lanes 0..31 carry
// 8 channels of pixel x-lo, lanes 32..63 of pixel x-hi. Halves the VMEM
// request count vs 16x512B (the round-7 hypothesis: per-CU outstanding
// request slots are the gather's service limit).
struct TapsP { uint4 t[8]; };

__device__ __forceinline__ void load_pairs(TapsP& T, const uint4* __restrict__ fp4,
                                           const int2* __restrict__ s_o,
                                           int m, int lane) {
#pragma unroll
    for (int s = 0; s < 4; ++s) {
        const int2 o = s_o[m + s];
        T.t[2 * s + 0] = fp4[o.x + lane];   // row y-lo pair
        T.t[2 * s + 1] = fp4[o.y + lane];   // row y-hi pair
    }
}

__device__ __forceinline__ void fma_store(const TapsP& T,
                                          const float4* __restrict__ s_w,
                                          int m, int j, int lane,
                                          float (&obuf)[8][32][NBINS]) {
    float a[8] = {0.f, 0.f, 0.f, 0.f, 0.f, 0.f, 0.f, 0.f};
    // per-half weights: s_w = (wlo_e0, whi_e0, wlo_e1, whi_e1); float2 view
    // index 2*(m+s) + (lane>>5) -> (.x = row-lo w, .y = row-hi w) for this half
    const float2* w2 = ((const float2*)s_w) + (lane >> 5);
#pragma unroll
    for (int s = 0; s < 4; ++s) {
        const float2 ws = w2[2 * (m + s)];
        mix8(a, T.t[2 * s + 0], ws.x);
        mix8(a, T.t[2 * s + 1], ws.y);
    }
    // combine the two half-waves (channel group q=lane&31 split across halves)
#pragma unroll
    for (int k = 0; k < 8; ++k) a[k] += __shfl_xor(a[k], 32, 64);
    if (lane < 32) {
        // channel c = 8*lane + k -> obuf[k][lane][j]; stride 49 dwords (odd)
#pragma unroll
        for (int k = 0; k < 8; ++k) obuf[k][lane][j] = a[k];
    }
}

// ---- gather from fp16 NHWC: one block (512 thr, 8 waves) per roi.
// Full-roi obuf -> ONE coalesced line-complete nontemporal writeout.
// 2-deep ping-pong pinned with sched_barrier (16 x 1024B in flight/wave).
// LDS 54.9KB -> 2 blocks/CU; launch_bounds(512,4) -> 128-VGPR budget.
__global__ __launch_bounds__(512, 4)
void gather_nhwc(const half_t* __restrict__ nhwc,
                 const float* __restrict__ rois,
                 const int* __restrict__ perm,
                 float* __restrict__ out) {
    __shared__ float  obuf[8][32][NBINS];   // 50176 B
    __shared__ int2   s_o[NMETA];           // 1568 B: pair base (uint4 units)
    __shared__ float4 s_w[NMETA];           // 3136 B: per-elem x per-row weights

    const int r    = perm[blockIdx.x];
    const int tid  = threadIdx.x;
    const int wave = tid >> 6;   // 0..7
    const int lane = tid & 63;

    // ---- phase 0: per-(bin,sample) metadata (196 of 512 threads) ----
    if (tid < NMETA) {
        const float* roi = rois + r * 6;
        const int   b     = (int)roi[0];
        const float cx    = roi[1] * SPATIAL_SCALE - 0.5f;   // ALIGNED
        const float cy    = roi[2] * SPATIAL_SCALE - 0.5f;
        const float rw    = roi[3] * SPATIAL_SCALE;
        const float rh    = roi[4] * SPATIAL_SCALE;
        const float theta = roi[5];                           // CLOCKWISE == False
        const float bin_h = rh * (1.0f / OUT_H);
        const float bin_w = rw * (1.0f / OUT_W);
        float st, ct;
        __sincosf(theta, &st, &ct);

        const int bin = tid >> 2;          // 0..48
        const int s   = tid & 3;           // 0..3
        const int ph  = bin / OUT_W, pw = bin % OUT_W;
        const int iy  = s >> 1,      ix = s & 1;

        const float yy = -rh * 0.5f + ((float)ph + ((float)iy + 0.5f) * 0.5f) * bin_h;
        const float xx = -rw * 0.5f + ((float)pw + ((float)ix + 0.5f) * 0.5f) * bin_w;
        float x = yy * st + xx * ct + cx;
        float y = yy * ct - xx * st + cy;

        const bool valid = (y > -1.0f) && (y < (float)H_) &&
                           (x > -1.0f) && (x < (float)W_);
        y = fmaxf(y, 0.0f);
        x = fmaxf(x, 0.0f);
        int yl = (int)y, xl = (int)x;
        int yh; float ly;
        if (yl >= H_ - 1) { yl = H_ - 1; yh = H_ - 1; ly = 0.0f; }
        else              { yh = yl + 1; ly = y - (float)yl; }
        // x pair: base xp with elements (xp, xp+1); clamp case re-bases to
        // (W-2, W-1) with elem0 weight 0 -> never OOB, never weights garbage.
        int xp; float e0, e1;
        if (xl >= W_ - 1) { xp = W_ - 2; e0 = 0.0f; e1 = 1.0f; }
        else              { xp = xl; const float lx = x - (float)xl;
                            e0 = 1.0f - lx; e1 = lx; }
        const float hy = 1.0f - ly;
        const float scale = valid ? (1.0f / NSAMP) : 0.0f;

        const int bplane = b * HW_;
        // uint4 index of the 1024B pair: pixel * (C_*2/16) = pixel * 32
        s_o[tid] = make_int2((bplane + yl * W_ + xp) * 32,
                             (bplane + yh * W_ + xp) * 32);
        // layout: (wlo_e0, whi_e0, wlo_e1, whi_e1) so float2[lane>>5] works
        s_w[tid] = make_float4(hy * e0 * scale, ly * e0 * scale,
                               hy * e1 * scale, ly * e1 * scale);
    }
    __syncthreads();

    const uint4* __restrict__ fp4 = (const uint4*)nhwc;

    // ---- ping-pong pipelined bin loop, schedule pinned by sched_barrier ----
    // Wave w owns bins w, w+8, ..., <49. Buffer A: w, w+16, w+32, w+48;
    // buffer B: w+8, w+24, w+40. All branch conditions wave-uniform.
    {
        TapsP A, B;
        int jA = wave;
        int jB = wave + 8;
        load_pairs(A, fp4, s_o, 4 * jA, lane);
        if (jB < NBINS) load_pairs(B, fp4, s_o, 4 * jB, lane);
        __builtin_amdgcn_sched_barrier(0);

        // stage 1
        fma_store(A, s_w, 4 * jA, jA, lane, obuf);
        jA += 16;
        if (jA < NBINS) load_pairs(A, fp4, s_o, 4 * jA, lane);
        __builtin_amdgcn_sched_barrier(0);
        if (jB < NBINS) {
            fma_store(B, s_w, 4 * jB, jB, lane, obuf);
            jB += 16;
            if (jB < NBINS) load_pairs(B, fp4, s_o, 4 * jB, lane);
            __builtin_amdgcn_sched_barrier(0);
        }
        // stage 2
        if (jA < NBINS) {
            fma_store(A, s_w, 4 * jA, jA, lane, obuf);
            jA += 16;
            if (jA < NBINS) load_pairs(A, fp4, s_o, 4 * jA, lane);
            __builtin_amdgcn_sched_barrier(0);
        }
        if (jB < NBINS) {
            fma_store(B, s_w, 4 * jB, jB, lane, obuf);
            jB += 16;
            if (jB < NBINS) load_pairs(B, fp4, s_o, 4 * jB, lane);
            __builtin_amdgcn_sched_barrier(0);
        }
        // stage 3
        if (jA < NBINS) {
            fma_store(A, s_w, 4 * jA, jA, lane, obuf);
            jA += 16;
            if (jA < NBINS) load_pairs(A, fp4, s_o, 4 * jA, lane);
            __builtin_amdgcn_sched_barrier(0);
        }
        if (jB < NBINS) {
            fma_store(B, s_w, 4 * jB, jB, lane, obuf);
            jB += 16;            // max start 15 -> last use at 47; no reload
        }
        // stage 4 (wave 0 only: jA == 48)
        if (jA < NBINS) {
            fma_store(A, s_w, 4 * jA, jA, lane, obuf);
        }
    }
    __syncthreads();

    // ---- single coalesced writeout: 12544 consecutive floats per roi ----
    // (write-once data: nontemporal, keep L2 for the tap band)
    float* out_r = out + (size_t)r * (C_ * NBINS);
    const int E = C_ * NBINS;            // 12544
#pragma unroll
    for (int i = 0; i < (E + 511) / 512; ++i) {
        const int f = tid + 512 * i;
        if (f < E) {
            const int c = f / NBINS;
            const int j = f - c * NBINS;
            __builtin_nontemporal_store(obuf[c & 7][c >> 3][j], &out_r[f]);
        }
    }
}

// ============================================================================
// Fallback path (round-0 structure, known-passing)
// ============================================================================

struct alignas(16) Samp {
    int o0, o1, o2, o3;
    float w0, w1, w2, w3;
};

__device__ __forceinline__ Samp compute_samp(const float* __restrict__ rois,
                                             int r, int ph, int pw, int s) {
    const float* roi = rois + r * 6;
    int   b     = (int)roi[0];
    float cx    = roi[1] * SPATIAL_SCALE - 0.5f;
    float cy    = roi[2] * SPATIAL_SCALE - 0.5f;
    float rw    = roi[3] * SPATIAL_SCALE;
    float rh    = roi[4] * SPATIAL_SCALE;
    float theta = roi[5];
    float bin_h = rh * (1.0f / OUT_H);
    float bin_w = rw * (1.0f / OUT_W);
    int iy = s / GS, ix = s % GS;
    float yy = -rh * 0.5f + ((float)ph + ((float)iy + 0.5f) * (1.0f / GS)) * bin_h;
    float xx = -rw * 0.5f + ((float)pw + ((float)ix + 0.5f) * (1.0f / GS)) * bin_w;
    float st = sinf(theta), ct = cosf(theta);
    float x = yy * st + xx * ct + cx;
    float y = yy * ct - xx * st + cy;
    bool valid = (y > -1.0f) && (y < (float)H_) && (x > -1.0f) && (x < (float)W_);
    y = fmaxf(y, 0.0f);
    x = fmaxf(x, 0.0f);
    int yl = (int)y;
    int xl = (int)x;
    int yh; float ly;
    if (yl >= H_ - 1) { yl = H_ - 1; yh = H_ - 1; ly = 0.0f; }
    else              { yh = yl + 1; ly = y - (float)yl; }
    int xh; float lx;
    if (xl >= W_ - 1) { xl = W_ - 1; xh = W_ - 1; lx = 0.0f; }
    else              { xh = xl + 1; lx = x - (float)xl; }
    float hy = 1.0f - ly, hx = 1.0f - lx;
    float scale = valid ? (1.0f / NSAMP) : 0.0f;
    Samp sp;
    int base = b * (C_ * H_ * W_);
    sp.o0 = base + yl * W_ + xl;
    sp.o1 = base + yl * W_ + xh;
    sp.o2 = base + yh * W_ + xl;
    sp.o3 = base + yh * W_ + xh;
    sp.w0 = hy * hx * scale;
    sp.w1 = hy * lx * scale;
    sp.w2 = ly * hx * scale;
    sp.w3 = ly * lx * scale;
    return sp;
}

__global__ __launch_bounds__(256)
void mono_kernel(const float* __restrict__ feat,
                 const float* __restrict__ rois,
                 float* __restrict__ out) {
    int tid = blockIdx.x * blockDim.x + threadIdx.x;
    if (tid >= R_ * C_ * NBINS) return;
    int bin = tid % NBINS;
    int rc  = tid / NBINS;
    int c   = rc % C_;
    int r   = rc / C_;
    int coff = c * (H_ * W_);
    float acc = 0.0f;
#pragma unroll
    for (int s = 0; s < NSAMP; ++s) {
        Samp t = compute_samp(rois, r, bin / OUT_W, bin % OUT_W, s);
        acc += t.w0 * feat[coff + t.o0];
        acc += t.w1 * feat[coff + t.o1];
        acc += t.w2 * feat[coff + t.o2];
        acc += t.w3 * feat[coff + t.o3];
    }
    out[tid] = acc;
}

// ============================================================================

extern "C" void kernel_launch(void* const* d_in, const int* in_sizes, int n_in,
                              void* d_out, int out_size, void* d_ws, size_t ws_size,
                              hipStream_t stream) {
    const float* feat = (const float*)d_in[0];
    const float* rois = (const float*)d_in[1];
    float* out = (float*)d_out;

    const size_t nhwc_bytes = (size_t)B_ * C_ * HW_ * sizeof(half_t);  // 41 MB
    const size_t perm_bytes = (size_t)R_ * sizeof(int);

    if (ws_size >= nhwc_bytes + perm_bytes) {
        half_t* nhwc = (half_t*)d_ws;
        int*    perm = (int*)((char*)d_ws + nhwc_bytes);
        dim3 tgrid(HW_ / 64, C_ / 64, B_);   // 625 x 4 x 2
        nchw_to_nhwc_h<<<tgrid, 256, 0, stream>>>(feat, nhwc, rois, perm);
        gather_nhwc<<<R_, 512, 0, stream>>>(nhwc, rois, perm, out);
    } else {
        const int n_out = R_ * C_ * NBINS;
        mono_kernel<<<(n_out + 255) / 256, 256, 0, stream>>>(feat, rois, out);
    }
}